// Round 5
// baseline (840.444 us; speedup 1.0000x reference)
//
#include <hip/hip_runtime.h>
#include <hip/hip_bf16.h>

// Problem constants
#define MROW 8192   // BATCH
#define DIMK 4096   // DIM (= K of both GEMMs)
#define NCOL 4096   // N_HEADS*HIDDEN = DIM
#define HID  256
#define NH   16
#define SEQL 4096

// GEMM tile geometry: 128x128 tile, BK=32, 4 waves (2M x 2N), 32x32x16 MFMA,
// ring-of-3 LDS (3 x 16KB = 48KB) -> 3 blocks/CU, 12 waves/CU.
#define BKT 32
#define NKT (DIMK / BKT)       // 128 K-tiles
#define SLOTB 16384            // ring slot: A 8KB + B 8KB
#define RING 3

typedef __attribute__((ext_vector_type(8)))  short short8;
typedef __attribute__((ext_vector_type(16))) float f32x16;

__device__ inline ushort f2bf(float f) {
  unsigned u = __float_as_uint(f);
  u += 0x7FFF + ((u >> 16) & 1);   // RNE
  return (ushort)(u >> 16);
}

__device__ inline void gload16(const void* g, void* l) {
  __builtin_amdgcn_global_load_lds(
      (const __attribute__((address_space(1))) void*)g,
      (__attribute__((address_space(3))) void*)l, 16, 0, 0);
}

// fp32 -> bf16, 8 elements/thread, grid-stride
__global__ void cvt_f32_bf16(const float* __restrict__ s, ushort* __restrict__ d, long n8) {
  long stride = (long)gridDim.x * blockDim.x;
  for (long i = (long)blockIdx.x * blockDim.x + threadIdx.x; i < n8; i += stride) {
    const float4* s4 = (const float4*)(s + i * 8);
    float4 a = s4[0], b = s4[1];
    ushort r[8] = {f2bf(a.x), f2bf(a.y), f2bf(a.z), f2bf(a.w),
                   f2bf(b.x), f2bf(b.y), f2bf(b.z), f2bf(b.w)};
    *(uint4*)(d + i * 8) = *(const uint4*)r;
  }
}

// per-output-column coefficients for the GEMM1 epilogue
__global__ void coef_kernel(const float* __restrict__ mix_w, const float* __restrict__ mix_b,
                            const float* __restrict__ decay_value, const float* __restrict__ proj_b,
                            const int* __restrict__ index_p,
                            float* __restrict__ wv, float* __restrict__ cc, float* __restrict__ pb2) {
  int n = blockIdx.x * blockDim.x + threadIdx.x;   // 0..4095
  if (n >= NCOL) return;
  int h = n >> 8;
  int idx = *index_p;
  float w  = mix_w[h * SEQL + idx];
  float bb = mix_b[h * SEQL + idx];
  float dv = fminf(fmaxf(decay_value[h], 0.9f), 1.0f);
  float decay = powf(dv, 0.125f);                  // 1/DECAY_CONSTANT (=8)
  float coef = (h < NH / 2) ? w * decay : decay;
  wv[n]  = w;
  cc[n]  = coef;
  pb2[n] = w * proj_b[n] + bb;
}

// C = A(MxK)*B^T(NxK), bf16, 32x32x16 MFMA. LDS tile row = 64B (32 bf16).
// Swizzle: 16B slot(row,c) = (c + (row>>1)) & 3 (rotation), applied inversely on
// the global source (linear LDS dest for global_load_lds) and forward on reads.
// Conflict-free for 32x32 fragment reads (8 lanes per 16B bank-set).
template <int EPI>
__global__ __launch_bounds__(256, 3) void gemm128(
    const ushort* __restrict__ A, const ushort* __restrict__ B,
    float* __restrict__ outf, ushort* __restrict__ outh,
    const float* __restrict__ cache, const float* __restrict__ wv,
    const float* __restrict__ cc, const float* __restrict__ pb2,
    const float* __restrict__ outb) {
  __shared__ __align__(16) char smem[RING * SLOTB];

  const int tid  = threadIdx.x;
  const int lane = tid & 63;
  const int wid  = tid >> 6;
  const int wm = wid >> 1, wn = wid & 1;
  const int l31 = lane & 31, khalf = lane >> 5;

  // XCD swizzle (grid 2048, 2048 % 8 == 0, bijective)
  const int bid = blockIdx.x;
  const int swz = (bid & 7) * 256 + (bid >> 3);
  const int bm = swz >> 5, bn = swz & 31;        // 64 x 32 tiles
  const int m0 = bm * 128, n0 = bn * 128;

  const ushort* Ag = A + (size_t)m0 * DIMK;
  const ushort* Bg = B + (size_t)n0 * DIMK;

  // ---- precomputed LDS read byte-offsets (loop-invariant)
  int aoff[2][2], boff[2][2];
#pragma unroll
  for (int mi = 0; mi < 2; ++mi)
#pragma unroll
    for (int ks = 0; ks < 2; ++ks) {
      int row = wm * 64 + mi * 32 + l31;
      int c   = ks * 2 + khalf;
      aoff[mi][ks] = row * 64 + (((c + (row >> 1)) & 3) << 4);
    }
#pragma unroll
  for (int ni = 0; ni < 2; ++ni)
#pragma unroll
    for (int ks = 0; ks < 2; ++ks) {
      int row = wn * 64 + ni * 32 + l31;
      int c   = ks * 2 + khalf;
      boff[ni][ks] = row * 64 + (((c + (row >> 1)) & 3) << 4);
    }

  // ---- precomputed stage offsets: LDS linear dest, inverse-swizzled global src
  int soff[2], sgo[2];
#pragma unroll
  for (int j = 0; j < 2; ++j) {
    int off = j * 4096 + tid * 16;               // [0, 8192)
    int row = off >> 6;
    int slot = (off >> 4) & 3;
    int c = (slot - (row >> 1)) & 3;
    soff[j] = off;
    sgo[j]  = row * DIMK + c * 8;                // element offset in panel
  }

  f32x16 acc[2][2] = {};

  // prologue: stage kt=0 -> slot0, kt=1 -> slot1
#pragma unroll
  for (int kt = 0; kt < 2; ++kt) {
    char* s = smem + kt * SLOTB;
#pragma unroll
    for (int j = 0; j < 2; ++j) {
      gload16(Ag + (size_t)sgo[j] + kt * BKT, s + soff[j]);
      gload16(Bg + (size_t)sgo[j] + kt * BKT, s + 8192 + soff[j]);
    }
  }
  asm volatile("s_waitcnt vmcnt(4)" ::: "memory");
  __builtin_amdgcn_s_barrier();
  __builtin_amdgcn_sched_barrier(0);

  int rcur = 0, rstg = 2;
  for (int kt = 0; kt < NKT; ++kt) {
    const char* cur = smem + rcur * SLOTB;

    short8 af[2][2], bf[2][2];
#pragma unroll
    for (int mi = 0; mi < 2; ++mi)
#pragma unroll
      for (int ks = 0; ks < 2; ++ks)
        af[mi][ks] = *(const short8*)(cur + aoff[mi][ks]);
#pragma unroll
    for (int ni = 0; ni < 2; ++ni)
#pragma unroll
      for (int ks = 0; ks < 2; ++ks)
        bf[ni][ks] = *(const short8*)(cur + 8192 + boff[ni][ks]);

    if (kt < NKT - 2) {
      char* st = smem + rstg * SLOTB;
      int k0 = (kt + 2) * BKT;
#pragma unroll
      for (int j = 0; j < 2; ++j) {
        gload16(Ag + (size_t)sgo[j] + k0, st + soff[j]);
        gload16(Bg + (size_t)sgo[j] + k0, st + 8192 + soff[j]);
      }
    }

    __builtin_amdgcn_s_setprio(1);
#pragma unroll
    for (int mi = 0; mi < 2; ++mi)
#pragma unroll
      for (int ni = 0; ni < 2; ++ni)
#pragma unroll
        for (int ks = 0; ks < 2; ++ks)
          acc[mi][ni] = __builtin_amdgcn_mfma_f32_32x32x16_bf16(
              af[mi][ks], bf[ni][ks], acc[mi][ni], 0, 0, 0);
    __builtin_amdgcn_s_setprio(0);

    // counted wait: guarantee kt+1 landed; keep kt+2 (4 loads) in flight.
    if (kt < NKT - 2)       asm volatile("s_waitcnt vmcnt(4)" ::: "memory");
    else if (kt == NKT - 2) asm volatile("s_waitcnt vmcnt(0)" ::: "memory");
    __builtin_amdgcn_s_barrier();
    __builtin_amdgcn_sched_barrier(0);

    rcur = (rcur == RING - 1) ? 0 : rcur + 1;
    rstg = (rstg == RING - 1) ? 0 : rstg + 1;
  }

  // ---- epilogue. C/D 32x32 map: col = l31, row = (reg&3) + 8*(reg>>2) + 4*khalf
  const int colb = n0 + wn * 64 + l31;
  const int rowb = m0 + wm * 64 + khalf * 4;

  float wvv[2], ccv[2], pbv[2], obv[2];
#pragma unroll
  for (int ni = 0; ni < 2; ++ni) {
    int n = colb + ni * 32;
    if (EPI == 1) { wvv[ni] = wv[n]; ccv[ni] = cc[n]; pbv[ni] = pb2[n]; }
    else          { obv[ni] = outb[n]; }
  }

#pragma unroll
  for (int mi = 0; mi < 2; ++mi) {
#pragma unroll
    for (int ni = 0; ni < 2; ++ni) {
      f32x16 v = acc[mi][ni];
      int n = colb + ni * 32;
#pragma unroll
      for (int reg = 0; reg < 16; ++reg) {
        int m = rowb + mi * 32 + (reg & 3) + ((reg >> 2) << 3);
        if (EPI == 1) {
          int h = n >> 8, kq = n & 255;
          float val = wvv[ni] * v[reg] + ccv[ni] * cache[((size_t)h * MROW + m) * HID + kq] + pbv[ni];
          outh[(size_t)m * NCOL + n] = f2bf(val);
        } else {
          outf[(size_t)m * NCOL + n] = v[reg] + obv[ni];
        }
      }
    }
  }
}

extern "C" void kernel_launch(void* const* d_in, const int* in_sizes, int n_in,
                              void* d_out, int out_size, void* d_ws, size_t ws_size,
                              hipStream_t stream) {
  const float* x      = (const float*)d_in[0];
  const float* proj_w = (const float*)d_in[1];
  const float* proj_b = (const float*)d_in[2];
  const float* mix_w  = (const float*)d_in[3];
  const float* mix_b  = (const float*)d_in[4];
  const float* decay  = (const float*)d_in[5];
  const float* cache  = (const float*)d_in[6];
  const float* out_w  = (const float*)d_in[7];
  const float* out_b  = (const float*)d_in[8];
  const int*   index  = (const int*)d_in[9];

  char* ws = (char*)d_ws;
  ushort* xb  = (ushort*)ws;                         // 8192*4096*2 = 64 MiB
  ushort* pwb = (ushort*)(ws + 67108864);            // 32 MiB
  ushort* owb = (ushort*)(ws + 100663296);           // 32 MiB
  ushort* hid = (ushort*)(ws + 134217728);           // 64 MiB
  float*  wv  = (float*)(ws + 201326592);
  float*  cc  = (float*)(ws + 201326592 + 16384);
  float*  pb2 = (float*)(ws + 201326592 + 32768);

  hipLaunchKernelGGL(cvt_f32_bf16, dim3(2048), dim3(256), 0, stream,
                     x, xb, (long)MROW * DIMK / 8);
  hipLaunchKernelGGL(cvt_f32_bf16, dim3(1024), dim3(256), 0, stream,
                     proj_w, pwb, (long)NCOL * DIMK / 8);
  hipLaunchKernelGGL(cvt_f32_bf16, dim3(1024), dim3(256), 0, stream,
                     out_w, owb, (long)NCOL * DIMK / 8);
  hipLaunchKernelGGL(coef_kernel, dim3(16), dim3(256), 0, stream,
                     mix_w, mix_b, decay, proj_b, index, wv, cc, pb2);

  // GEMM1: hidden = mix(x @ proj_w^T) -> bf16
  hipLaunchKernelGGL((gemm128<1>), dim3((MROW / 128) * (NCOL / 128)), dim3(256), 0, stream,
                     xb, pwb, nullptr, hid, cache, wv, cc, pb2, nullptr);
  // GEMM2: out = hidden @ out_w^T + out_b -> f32
  hipLaunchKernelGGL((gemm128<0>), dim3((MROW / 128) * (NCOL / 128)), dim3(256), 0, stream,
                     hid, owb, (float*)d_out, nullptr, nullptr, nullptr, nullptr, nullptr, out_b);
}

// Round 6
// 596.696 us; speedup vs baseline: 1.4085x; 1.4085x over previous
//
#include <hip/hip_runtime.h>
#include <hip/hip_bf16.h>

// Problem constants
#define MROW 8192   // BATCH
#define DIMK 4096   // DIM (= K of both GEMMs)
#define NCOL 4096   // N_HEADS*HIDDEN = DIM
#define HID  256
#define NH   16
#define SEQL 4096

// GEMM tile geometry: 256x256 tile, BK=32, 16 waves (4M x 4N, wave-tile 64x64),
// ring-of-4 LDS (4 x 32KB = 128KB), one 1024-thread block per CU.
#define BKT 32
#define NKT (DIMK / BKT)       // 128 K-tiles
#define SLOTB 32768            // ring slot: A 16KB + B 16KB
#define LDS_TOTAL (4 * SLOTB)  // 131072

typedef __attribute__((ext_vector_type(8))) short short8;
typedef __attribute__((ext_vector_type(4))) float f32x4;

__device__ inline ushort f2bf(float f) {
  unsigned u = __float_as_uint(f);
  u += 0x7FFF + ((u >> 16) & 1);   // RNE
  return (ushort)(u >> 16);
}

__device__ inline void gload16(const void* g, void* l) {
  __builtin_amdgcn_global_load_lds(
      (const __attribute__((address_space(1))) void*)g,
      (__attribute__((address_space(3))) void*)l, 16, 0, 0);
}

// fp32 -> bf16, 8 elements/thread, grid-stride
__global__ void cvt_f32_bf16(const float* __restrict__ s, ushort* __restrict__ d, long n8) {
  long stride = (long)gridDim.x * blockDim.x;
  for (long i = (long)blockIdx.x * blockDim.x + threadIdx.x; i < n8; i += stride) {
    const float4* s4 = (const float4*)(s + i * 8);
    float4 a = s4[0], b = s4[1];
    ushort r[8] = {f2bf(a.x), f2bf(a.y), f2bf(a.z), f2bf(a.w),
                   f2bf(b.x), f2bf(b.y), f2bf(b.z), f2bf(b.w)};
    *(uint4*)(d + i * 8) = *(const uint4*)r;
  }
}

// per-output-column coefficients for the GEMM1 epilogue
__global__ void coef_kernel(const float* __restrict__ mix_w, const float* __restrict__ mix_b,
                            const float* __restrict__ decay_value, const float* __restrict__ proj_b,
                            const int* __restrict__ index_p,
                            float* __restrict__ wv, float* __restrict__ cc, float* __restrict__ pb2) {
  int n = blockIdx.x * blockDim.x + threadIdx.x;   // 0..4095
  if (n >= NCOL) return;
  int h = n >> 8;
  int idx = *index_p;
  float w  = mix_w[h * SEQL + idx];
  float bb = mix_b[h * SEQL + idx];
  float dv = fminf(fmaxf(decay_value[h], 0.9f), 1.0f);
  float decay = powf(dv, 0.125f);                  // 1/DECAY_CONSTANT (=8)
  float coef = (h < NH / 2) ? w * decay : decay;
  wv[n]  = w;
  cc[n]  = coef;
  pb2[n] = w * proj_b[n] + bb;
}

// C = A(MxK)*B^T(NxK), bf16, 16x16x32 MFMA. LDS tile row = 64B (32 bf16),
// swizzle: 16B slot = c ^ ((row>>1)&3) (round-4 layout, measured 0 conflicts),
// applied inversely on the global source (linear LDS dest), forward on reads.
// 16 waves, one barrier per K-tile, counted vmcnt, ring-of-4.
template <int EPI>
__global__ __launch_bounds__(1024, 4) void gemm256(
    const ushort* __restrict__ A, const ushort* __restrict__ B,
    float* __restrict__ outf, ushort* __restrict__ outh,
    const float* __restrict__ cache, const float* __restrict__ wv,
    const float* __restrict__ cc, const float* __restrict__ pb2,
    const float* __restrict__ outb) {
  extern __shared__ __align__(16) char smem[];

  const int tid  = threadIdx.x;
  const int lane = tid & 63;
  const int wid  = tid >> 6;      // 0..15
  const int wr = wid >> 2;        // 0..3 (M)
  const int wc = wid & 3;         // 0..3 (N)
  const int r16 = lane & 15;
  const int cq  = lane >> 4;      // 16B column block 0..3

  // XCD swizzle (grid 512, bijective)
  const int bid = blockIdx.x;
  const int swz = (bid & 7) * 64 + (bid >> 3);
  const int bm = swz >> 4, bn = swz & 15;   // 32 x 16 tiles
  const int m0 = bm * 256, n0 = bn * 256;

  const ushort* Ag = A + (size_t)m0 * DIMK;
  const ushort* Bg = B + (size_t)n0 * DIMK;

  // ---- precomputed LDS read byte-offsets (loop-invariant; swizzled)
  int aoff[4], boff[4];
#pragma unroll
  for (int i = 0; i < 4; ++i) {
    int arow = wr * 64 + i * 16 + r16;
    aoff[i] = arow * 64 + ((cq ^ ((arow >> 1) & 3)) << 4);
    int brow = wc * 64 + i * 16 + r16;
    boff[i] = 16384 + brow * 64 + ((cq ^ ((brow >> 1) & 3)) << 4);
  }

  // ---- precomputed stage offsets: linear LDS dest, inverse-swizzled global src
  const int soff = tid * 16;                 // [0, 16384)
  const int srow = soff >> 6;
  const int sgo  = srow * DIMK + ((((soff >> 4) & 3) ^ ((srow >> 1) & 3)) << 3);

  f32x4 acc[4][4] = {};

  // prologue: stage K-tiles 0..2 into ring slots 0..2 (2 loads per thread per kt)
#pragma unroll
  for (int kt = 0; kt < 3; ++kt) {
    char* s = smem + kt * SLOTB;
    gload16(Ag + (size_t)sgo + kt * BKT, s + soff);
    gload16(Bg + (size_t)sgo + kt * BKT, s + 16384 + soff);
  }
  asm volatile("s_waitcnt vmcnt(4)" ::: "memory");
  __builtin_amdgcn_s_barrier();
  __builtin_amdgcn_sched_barrier(0);

  for (int kt = 0; kt < NKT; ++kt) {
    const char* cur = smem + (kt & 3) * SLOTB;

    short8 af[4], bf[4];
#pragma unroll
    for (int i = 0; i < 4; ++i) bf[i] = *(const short8*)(cur + boff[i]);
#pragma unroll
    for (int i = 0; i < 4; ++i) af[i] = *(const short8*)(cur + aoff[i]);

    // prefetch K-tile kt+3 into ring slot (kt+3)&3 (= (kt-1)&3, consumed last iter)
    if (kt < NKT - 3) {
      char* st = smem + ((kt + 3) & 3) * SLOTB;
      int k0 = (kt + 3) * BKT;
      gload16(Ag + (size_t)sgo + k0, st + soff);
      gload16(Bg + (size_t)sgo + k0, st + 16384 + soff);
    }

    __builtin_amdgcn_s_setprio(1);
#pragma unroll
    for (int mi = 0; mi < 4; ++mi)
#pragma unroll
      for (int ni = 0; ni < 4; ++ni)
        acc[mi][ni] = __builtin_amdgcn_mfma_f32_16x16x32_bf16(af[mi], bf[ni], acc[mi][ni], 0, 0, 0);
    __builtin_amdgcn_s_setprio(0);

    // counted wait: guarantee kt+1 landed; keep deeper prefetch in flight.
    if (kt < NKT - 3)       asm volatile("s_waitcnt vmcnt(4)" ::: "memory");
    else if (kt == NKT - 3) asm volatile("s_waitcnt vmcnt(2)" ::: "memory");
    else if (kt == NKT - 2) asm volatile("s_waitcnt vmcnt(0)" ::: "memory");
    __builtin_amdgcn_s_barrier();
    __builtin_amdgcn_sched_barrier(0);
  }

  // ---- epilogue. C/D 16x16 map: col = lane&15, row = (lane>>4)*4 + reg
  const int colb = n0 + wc * 64 + r16;
  const int rowb = m0 + wr * 64 + cq * 4;

  float wvv[4], ccv[4], pbv[4], obv[4];
#pragma unroll
  for (int ni = 0; ni < 4; ++ni) {
    int n = colb + ni * 16;
    if (EPI == 1) { wvv[ni] = wv[n]; ccv[ni] = cc[n]; pbv[ni] = pb2[n]; }
    else          { obv[ni] = outb[n]; }
  }

#pragma unroll
  for (int mi = 0; mi < 4; ++mi) {
#pragma unroll
    for (int ni = 0; ni < 4; ++ni) {
      f32x4 v = acc[mi][ni];
      int n = colb + ni * 16;
#pragma unroll
      for (int r = 0; r < 4; ++r) {
        int m = rowb + mi * 16 + r;
        if (EPI == 1) {
          int h = n >> 8, kq = n & 255;
          float val = wvv[ni] * v[r] + ccv[ni] * cache[((size_t)h * MROW + m) * HID + kq] + pbv[ni];
          outh[(size_t)m * NCOL + n] = f2bf(val);
        } else {
          outf[(size_t)m * NCOL + n] = v[r] + obv[ni];
        }
      }
    }
  }
}

extern "C" void kernel_launch(void* const* d_in, const int* in_sizes, int n_in,
                              void* d_out, int out_size, void* d_ws, size_t ws_size,
                              hipStream_t stream) {
  const float* x      = (const float*)d_in[0];
  const float* proj_w = (const float*)d_in[1];
  const float* proj_b = (const float*)d_in[2];
  const float* mix_w  = (const float*)d_in[3];
  const float* mix_b  = (const float*)d_in[4];
  const float* decay  = (const float*)d_in[5];
  const float* cache  = (const float*)d_in[6];
  const float* out_w  = (const float*)d_in[7];
  const float* out_b  = (const float*)d_in[8];
  const int*   index  = (const int*)d_in[9];

  char* ws = (char*)d_ws;
  ushort* xb  = (ushort*)ws;                         // 8192*4096*2 = 64 MiB
  ushort* pwb = (ushort*)(ws + 67108864);            // 32 MiB
  ushort* owb = (ushort*)(ws + 100663296);           // 32 MiB
  ushort* hid = (ushort*)(ws + 134217728);           // 64 MiB
  float*  wv  = (float*)(ws + 201326592);
  float*  cc  = (float*)(ws + 201326592 + 16384);
  float*  pb2 = (float*)(ws + 201326592 + 32768);

  hipFuncSetAttribute((const void*)&gemm256<1>, hipFuncAttributeMaxDynamicSharedMemorySize, LDS_TOTAL);
  hipFuncSetAttribute((const void*)&gemm256<0>, hipFuncAttributeMaxDynamicSharedMemorySize, LDS_TOTAL);

  hipLaunchKernelGGL(cvt_f32_bf16, dim3(2048), dim3(256), 0, stream,
                     x, xb, (long)MROW * DIMK / 8);
  hipLaunchKernelGGL(cvt_f32_bf16, dim3(1024), dim3(256), 0, stream,
                     proj_w, pwb, (long)NCOL * DIMK / 8);
  hipLaunchKernelGGL(cvt_f32_bf16, dim3(1024), dim3(256), 0, stream,
                     out_w, owb, (long)NCOL * DIMK / 8);
  hipLaunchKernelGGL(coef_kernel, dim3(16), dim3(256), 0, stream,
                     mix_w, mix_b, decay, proj_b, index, wv, cc, pb2);

  // GEMM1: hidden = mix(x @ proj_w^T) -> bf16
  hipLaunchKernelGGL((gemm256<1>), dim3((MROW / 256) * (NCOL / 256)), dim3(1024), LDS_TOTAL, stream,
                     xb, pwb, nullptr, hid, cache, wv, cc, pb2, nullptr);
  // GEMM2: out = hidden @ out_w^T + out_b -> f32
  hipLaunchKernelGGL((gemm256<0>), dim3((MROW / 256) * (NCOL / 256)), dim3(1024), LDS_TOTAL, stream,
                     hid, owb, (float*)d_out, nullptr, nullptr, nullptr, nullptr, nullptr, out_b);
}